// Round 1
// baseline (2709.005 us; speedup 1.0000x reference)
//
#include <hip/hip_runtime.h>
#include <cstdint>

// ODEBlock: 16 RK4 steps of f(t,y) = tanh(y@W1 + b1 + t) @ W2 + b2
// B=1024 (M), D=512, H=2048. bf16 MFMA GEMMs with fp32 state/epilogues.

typedef __bf16 bf16x8 __attribute__((ext_vector_type(8)));
typedef float f32x4 __attribute__((ext_vector_type(4)));

#define AS1 __attribute__((address_space(1)))
#define AS3 __attribute__((address_space(3)))

#define MDIM 1024
#define DDIM 512
#define HDIM 2048

__device__ __forceinline__ void async_copy16(const void* g, void* lds) {
  __builtin_amdgcn_global_load_lds((const AS1 void*)g, (AS3 void*)lds, 16, 0, 0);
}

__device__ __forceinline__ unsigned short f32_to_bf16(float f) {
  union { float f; unsigned u; } c; c.f = f;
  unsigned u = c.u + 0x7FFFu + ((c.u >> 16) & 1u);   // RNE
  return (unsigned short)(u >> 16);
}

__device__ __forceinline__ float tanh_fast(float x) {
  float a = __builtin_fabsf(x);
  float e = __expf(-2.0f * a);                        // in (0,1], no overflow
  float r = (1.0f - e) * __builtin_amdgcn_rcpf(1.0f + e);
  return __builtin_copysignf(r, x);
}

// ---- transpose + f32->bf16: out[c*R + r] = bf16(in[r*C + c]) --------------
__global__ __launch_bounds__(256) void transpose_bf16_kernel(
    const float* __restrict__ in, unsigned short* __restrict__ out, int R, int C) {
  __shared__ float tile[64][65];
  int nbc = C >> 6;
  int br = blockIdx.x / nbc, bc = blockIdx.x % nbc;
  int r0 = br * 64, c0 = bc * 64;
  int tr = threadIdx.x >> 6;       // 0..3
  int tc = threadIdx.x & 63;
  for (int i = 0; i < 16; ++i) {
    int row = i * 4 + tr;
    tile[row][tc] = in[(r0 + row) * C + c0 + tc];
  }
  __syncthreads();
  for (int i = 0; i < 16; ++i) {
    int row = i * 4 + tr;          // row of transposed tile = source col
    out[(c0 + row) * R + r0 + tc] = f32_to_bf16(tile[tc][row]);
  }
}

// ---- init: y = x (fp32, lives in d_out), arg = bf16(x) --------------------
__global__ __launch_bounds__(256) void init_kernel(
    const float* __restrict__ x, float* __restrict__ y,
    unsigned short* __restrict__ arg) {
  int i = blockIdx.x * 256 + threadIdx.x;
  float v = x[i];
  y[i] = v;
  arg[i] = f32_to_bf16(v);
}

// ---- GEMM1: H = tanh(arg[1024,512] @ W1 + b1 + t), W1T [2048,512] bf16 ----
// tile BM=64 BN=128 BK=64, grid 16x16=256 blocks, 4 waves (2x2), wave 32x64
__global__ __launch_bounds__(256, 2) void gemm1_kernel(
    const unsigned short* __restrict__ A,    // arg bf16 [1024,512]
    const unsigned short* __restrict__ Bt,   // W1T bf16 [2048,512]
    const float* __restrict__ b1, float tval,
    unsigned short* __restrict__ H)          // [1024,2048] bf16
{
  __shared__ bf16x8 sA[64 * 8];    // [row][kgrp], 8KB
  __shared__ bf16x8 sB[128 * 8];   // 16KB
  const int K = DDIM;
  int bid = blockIdx.x;
  int bm = bid >> 4;               // 0..15
  int bn = bid & 15;               // 0..15
  int tid = threadIdx.x;
  int lane = tid & 63;
  int wid = tid >> 6;
  int wm = (wid >> 1) * 32;
  int wn = (wid & 1) * 64;
  int srow = tid >> 3;             // 0..31
  int scol = (tid & 7) * 8;        // element col, mult of 8
  const unsigned short* gA = A + (bm * 64 + srow) * K + scol;
  const unsigned short* gB = Bt + (bn * 128 + srow) * K + scol;
  int lds0 = srow * 8 + (scol >> 3);   // bf16x8 units == tid*16 bytes
  f32x4 acc[2][4] = {};
  for (int kt = 0; kt < K; kt += 64) {
    __syncthreads();
    async_copy16(gA + kt, &sA[lds0]);
    async_copy16(gA + 32 * K + kt, &sA[lds0 + 32 * 8]);
    for (int r = 0; r < 4; ++r)
      async_copy16(gB + r * 32 * K + kt, &sB[lds0 + r * 32 * 8]);
    __syncthreads();
    for (int ks = 0; ks < 2; ++ks) {
      int kg = ks * 4 + (lane >> 4);   // k-group 0..7
      bf16x8 af[2], bfr[4];
      for (int i = 0; i < 2; ++i)
        af[i] = sA[(wm + i * 16 + (lane & 15)) * 8 + kg];
      for (int j = 0; j < 4; ++j)
        bfr[j] = sB[(wn + j * 16 + (lane & 15)) * 8 + kg];
      for (int i = 0; i < 2; ++i)
        for (int j = 0; j < 4; ++j)
          acc[i][j] = __builtin_amdgcn_mfma_f32_16x16x32_bf16(
              af[i], bfr[j], acc[i][j], 0, 0, 0);
    }
  }
  // D(m,n): m = (lane>>4)*4 + reg, n = lane&15
  int row0 = bm * 64 + wm + ((lane >> 4) << 2);
  int col0 = bn * 128 + wn + (lane & 15);
  float bias[4];
  for (int j = 0; j < 4; ++j) bias[j] = b1[col0 + j * 16] + tval;
  for (int i = 0; i < 2; ++i)
    for (int r = 0; r < 4; ++r) {
      int row = row0 + i * 16 + r;
      unsigned short* Hrow = H + row * HDIM + col0;
      for (int j = 0; j < 4; ++j)
        Hrow[j * 16] = f32_to_bf16(tanh_fast(acc[i][j][r] + bias[j]));
    }
}

// ---- GEMM2: k = H[1024,2048] @ W2 + b2, fused RK4 epilogue ----------------
// W2T [512,2048] bf16. tile 64x64 BK=64, grid 16x8=128, 4 waves, wave 32x32
// mode 0: kacc = k;        arg = bf16(y + dt/2*k)
// mode 1: kacc += 2k;      arg = bf16(y + dt/2*k)
// mode 2: kacc += 2k;      arg = bf16(y + dt*k)
// mode 3: y += dt/6*(kacc + k); arg = bf16(y_new)
__global__ __launch_bounds__(256, 2) void gemm2_kernel(
    const unsigned short* __restrict__ A,    // H bf16
    const unsigned short* __restrict__ Bt,   // W2T bf16
    const float* __restrict__ b2,
    float* __restrict__ y,                   // d_out, fp32 state
    float* __restrict__ kacc,
    unsigned short* __restrict__ arg,
    int mode, float dt)
{
  __shared__ bf16x8 sA[64 * 8];
  __shared__ bf16x8 sB[64 * 8];
  const int K = HDIM;
  int bid = blockIdx.x;
  int bm = bid >> 3;
  int bn = bid & 7;
  int tid = threadIdx.x;
  int lane = tid & 63;
  int wid = tid >> 6;
  int wm = (wid >> 1) * 32;
  int wn = (wid & 1) * 32;
  int srow = tid >> 3;
  int scol = (tid & 7) * 8;
  const unsigned short* gA = A + (bm * 64 + srow) * K + scol;
  const unsigned short* gB = Bt + (bn * 64 + srow) * K + scol;
  int lds0 = srow * 8 + (scol >> 3);
  f32x4 acc[2][2] = {};
  for (int kt = 0; kt < K; kt += 64) {
    __syncthreads();
    async_copy16(gA + kt, &sA[lds0]);
    async_copy16(gA + 32 * K + kt, &sA[lds0 + 32 * 8]);
    async_copy16(gB + kt, &sB[lds0]);
    async_copy16(gB + 32 * K + kt, &sB[lds0 + 32 * 8]);
    __syncthreads();
    for (int ks = 0; ks < 2; ++ks) {
      int kg = ks * 4 + (lane >> 4);
      bf16x8 af[2], bfr[2];
      for (int i = 0; i < 2; ++i)
        af[i] = sA[(wm + i * 16 + (lane & 15)) * 8 + kg];
      for (int j = 0; j < 2; ++j)
        bfr[j] = sB[(wn + j * 16 + (lane & 15)) * 8 + kg];
      for (int i = 0; i < 2; ++i)
        for (int j = 0; j < 2; ++j)
          acc[i][j] = __builtin_amdgcn_mfma_f32_16x16x32_bf16(
              af[i], bfr[j], acc[i][j], 0, 0, 0);
    }
  }
  int row0 = bm * 64 + wm + ((lane >> 4) << 2);
  int col0 = bn * 64 + wn + (lane & 15);
  float half_dt = 0.5f * dt;
  float dt6 = dt * (1.0f / 6.0f);
  float bias[2];
  for (int j = 0; j < 2; ++j) bias[j] = b2[col0 + j * 16];
  for (int i = 0; i < 2; ++i)
    for (int r = 0; r < 4; ++r) {
      int row = row0 + i * 16 + r;
      for (int j = 0; j < 2; ++j) {
        int col = col0 + j * 16;
        int idx = row * DDIM + col;
        float k = acc[i][j][r] + bias[j];
        float argv;
        if (mode == 0) {
          kacc[idx] = k;
          argv = y[idx] + half_dt * k;
        } else if (mode == 1) {
          kacc[idx] += 2.0f * k;
          argv = y[idx] + half_dt * k;
        } else if (mode == 2) {
          kacc[idx] += 2.0f * k;
          argv = y[idx] + dt * k;
        } else {
          float yn = y[idx] + dt6 * (kacc[idx] + k);
          y[idx] = yn;
          argv = yn;
        }
        arg[idx] = f32_to_bf16(argv);
      }
    }
}

extern "C" void kernel_launch(void* const* d_in, const int* in_sizes, int n_in,
                              void* d_out, int out_size, void* d_ws, size_t ws_size,
                              hipStream_t stream) {
  (void)in_sizes; (void)n_in; (void)out_size; (void)ws_size;
  const float* x  = (const float*)d_in[0];   // [1024,512]
  const float* W1 = (const float*)d_in[1];   // [512,2048]
  const float* b1 = (const float*)d_in[2];   // [2048]
  const float* W2 = (const float*)d_in[3];   // [2048,512]
  const float* b2 = (const float*)d_in[4];   // [512]
  float* y = (float*)d_out;                  // fp32 state lives in d_out

  char* ws = (char*)d_ws;
  unsigned short* W1T  = (unsigned short*)(ws);                    // 2MB  [2048,512] bf16
  unsigned short* W2T  = (unsigned short*)(ws + (2u << 20));       // 2MB  [512,2048] bf16
  unsigned short* Hbuf = (unsigned short*)(ws + (4u << 20));       // 4MB  [1024,2048] bf16
  unsigned short* arg  = (unsigned short*)(ws + (8u << 20));       // 1MB  [1024,512] bf16
  float*          kacc = (float*)(ws + (9u << 20));                // 2MB  [1024,512] f32
  // total 11MB

  transpose_bf16_kernel<<<256, 256, 0, stream>>>(W1, W1T, DDIM, HDIM);
  transpose_bf16_kernel<<<256, 256, 0, stream>>>(W2, W2T, HDIM, DDIM);
  init_kernel<<<MDIM * DDIM / 256, 256, 0, stream>>>(x, y, arg);

  const float dt = 1.0f / 16.0f;
  for (int n = 0; n < 16; ++n) {
    float t0 = dt * (float)n;
    const float ts[4] = {t0, t0 + 0.5f * dt, t0 + 0.5f * dt, t0 + dt};
    for (int s = 0; s < 4; ++s) {
      gemm1_kernel<<<256, 256, 0, stream>>>(arg, W1T, b1, ts[s], Hbuf);
      gemm2_kernel<<<128, 256, 0, stream>>>(Hbuf, W2T, b2, y, kacc, arg, s, dt);
    }
  }
}

// Round 2
// 1593.039 us; speedup vs baseline: 1.7005x; 1.7005x over previous
//
#include <hip/hip_runtime.h>
#include <cstdint>

// ODEBlock: 16 RK4 steps of f(t,y) = tanh(y@W1 + b1 + t) @ W2 + b2
// B=1024 (M), D=512, H=2048. bf16 MFMA GEMMs, fp32 state/epilogues.
// R1: 64x64 tiles both GEMMs (2 blocks/CU), explicit LDS double-buffer,
//     gemm2 split-K=4 + fused RK4 combine kernel.

typedef __bf16 bf16x8 __attribute__((ext_vector_type(8)));
typedef float f32x4 __attribute__((ext_vector_type(4)));

#define AS1 __attribute__((address_space(1)))
#define AS3 __attribute__((address_space(3)))

#define MDIM 1024
#define DDIM 512
#define HDIM 2048

__device__ __forceinline__ void async_copy16(const void* g, void* lds) {
  __builtin_amdgcn_global_load_lds((const AS1 void*)g, (AS3 void*)lds, 16, 0, 0);
}

__device__ __forceinline__ unsigned short f32_to_bf16(float f) {
  union { float f; unsigned u; } c; c.f = f;
  unsigned u = c.u + 0x7FFFu + ((c.u >> 16) & 1u);   // RNE
  return (unsigned short)(u >> 16);
}

__device__ __forceinline__ float tanh_fast(float x) {
  float a = __builtin_fabsf(x);
  float e = __expf(-2.0f * a);                        // in (0,1], no overflow
  float r = (1.0f - e) * __builtin_amdgcn_rcpf(1.0f + e);
  return __builtin_copysignf(r, x);
}

// ---- transpose + f32->bf16: out[c*R + r] = bf16(in[r*C + c]) --------------
__global__ __launch_bounds__(256) void transpose_bf16_kernel(
    const float* __restrict__ in, unsigned short* __restrict__ out, int R, int C) {
  __shared__ float tile[64][65];
  int nbc = C >> 6;
  int br = blockIdx.x / nbc, bc = blockIdx.x % nbc;
  int r0 = br * 64, c0 = bc * 64;
  int tr = threadIdx.x >> 6;       // 0..3
  int tc = threadIdx.x & 63;
  for (int i = 0; i < 16; ++i) {
    int row = i * 4 + tr;
    tile[row][tc] = in[(r0 + row) * C + c0 + tc];
  }
  __syncthreads();
  for (int i = 0; i < 16; ++i) {
    int row = i * 4 + tr;          // row of transposed tile = source col
    out[(c0 + row) * R + r0 + tc] = f32_to_bf16(tile[tc][row]);
  }
}

// ---- init: y = x (fp32, lives in d_out), arg = bf16(x) --------------------
__global__ __launch_bounds__(256) void init_kernel(
    const float* __restrict__ x, float* __restrict__ y,
    unsigned short* __restrict__ arg) {
  int i = blockIdx.x * 256 + threadIdx.x;
  float v = x[i];
  y[i] = v;
  arg[i] = f32_to_bf16(v);
}

// ---- GEMM1: H = tanh(arg[1024,512] @ W1T' + b1 + t) -----------------------
// W1T [2048,512] bf16 (K-contig). Tile 64x64, BK=64, grid 16x32=512 blocks,
// 4 waves (2x2), wave 32x32. Double-buffered LDS: loads for iter k+1 issued
// before compute of iter k; barrier at loop top drains them one iter later.
__global__ __launch_bounds__(256, 2) void gemm1_kernel(
    const unsigned short* __restrict__ A,    // arg bf16 [1024,512]
    const unsigned short* __restrict__ Bt,   // W1T bf16 [2048,512]
    const float* __restrict__ b1, float tval,
    unsigned short* __restrict__ H)          // [1024,2048] bf16
{
  __shared__ bf16x8 sA[2][64 * 8];   // 2 x 8KB
  __shared__ bf16x8 sB[2][64 * 8];   // 2 x 8KB
  const int K = DDIM;
  const int NITER = DDIM / 64;       // 8
  int bid = blockIdx.x;
  int bm = bid >> 5;                 // 0..15
  int bn = bid & 31;                 // 0..31
  int tid = threadIdx.x;
  int lane = tid & 63;
  int wid = tid >> 6;
  int wm = (wid >> 1) * 32;
  int wn = (wid & 1) * 32;
  int srow = tid >> 3;               // 0..31
  int scolb = tid & 7;               // bf16x8 unit 0..7
  const unsigned short* gA = A + (bm * 64 + srow) * K + scolb * 8;
  const unsigned short* gB = Bt + (bn * 64 + srow) * K + scolb * 8;
  int lds0 = srow * 8 + scolb;
  f32x4 acc[2][2] = {};

  // prologue: stage iter 0 into buffer 0
  async_copy16(gA, &sA[0][lds0]);
  async_copy16(gA + 32 * K, &sA[0][lds0 + 256]);
  async_copy16(gB, &sB[0][lds0]);
  async_copy16(gB + 32 * K, &sB[0][lds0 + 256]);

#pragma unroll 1
  for (int kt = 0; kt < NITER; ++kt) {
    int cur = kt & 1;
    __syncthreads();                 // drains buffer[cur] loads (issued 1 iter ago)
    if (kt + 1 < NITER) {
      int nxt = cur ^ 1;
      int off = (kt + 1) * 64;
      async_copy16(gA + off, &sA[nxt][lds0]);
      async_copy16(gA + 32 * K + off, &sA[nxt][lds0 + 256]);
      async_copy16(gB + off, &sB[nxt][lds0]);
      async_copy16(gB + 32 * K + off, &sB[nxt][lds0 + 256]);
    }
#pragma unroll
    for (int ks = 0; ks < 2; ++ks) {
      int kg = ks * 4 + (lane >> 4);
      bf16x8 af[2], bfr[2];
      for (int i = 0; i < 2; ++i)
        af[i] = sA[cur][(wm + i * 16 + (lane & 15)) * 8 + kg];
      for (int j = 0; j < 2; ++j)
        bfr[j] = sB[cur][(wn + j * 16 + (lane & 15)) * 8 + kg];
      for (int i = 0; i < 2; ++i)
        for (int j = 0; j < 2; ++j)
          acc[i][j] = __builtin_amdgcn_mfma_f32_16x16x32_bf16(
              af[i], bfr[j], acc[i][j], 0, 0, 0);
    }
  }
  // D(m,n): m = (lane>>4)*4 + reg, n = lane&15
  int row0 = bm * 64 + wm + ((lane >> 4) << 2);
  int col0 = bn * 64 + wn + (lane & 15);
  float bias[2];
  for (int j = 0; j < 2; ++j) bias[j] = b1[col0 + j * 16] + tval;
  for (int i = 0; i < 2; ++i)
    for (int r = 0; r < 4; ++r) {
      unsigned short* Hrow = H + (row0 + i * 16 + r) * HDIM + col0;
      for (int j = 0; j < 2; ++j)
        Hrow[j * 16] = f32_to_bf16(tanh_fast(acc[i][j][r] + bias[j]));
    }
}

// ---- GEMM2 split-K: part[s] = H[:, s*512:(s+1)*512] @ W2T'[:, chunk] ------
// W2T [512,2048] bf16. Tile 64x64, BK=64, splitK=4, grid 4*16*8=512 blocks.
__global__ __launch_bounds__(256, 2) void gemm2_kernel(
    const unsigned short* __restrict__ A,    // H bf16 [1024,2048]
    const unsigned short* __restrict__ Bt,   // W2T bf16 [512,2048]
    float* __restrict__ part)                // [4][1024,512] fp32
{
  __shared__ bf16x8 sA[2][64 * 8];
  __shared__ bf16x8 sB[2][64 * 8];
  const int K = HDIM;
  const int NITER = 8;                 // 512 K-chunk / 64
  int bid = blockIdx.x;
  int s = bid >> 7;                    // split-K index 0..3
  int rem = bid & 127;
  int bm = rem >> 3;                   // 0..15
  int bn = rem & 7;                    // 0..7
  int tid = threadIdx.x;
  int lane = tid & 63;
  int wid = tid >> 6;
  int wm = (wid >> 1) * 32;
  int wn = (wid & 1) * 32;
  int srow = tid >> 3;
  int scolb = tid & 7;
  int k0 = s * 512;
  const unsigned short* gA = A + (bm * 64 + srow) * K + k0 + scolb * 8;
  const unsigned short* gB = Bt + (bn * 64 + srow) * K + k0 + scolb * 8;
  int lds0 = srow * 8 + scolb;
  f32x4 acc[2][2] = {};

  async_copy16(gA, &sA[0][lds0]);
  async_copy16(gA + 32 * K, &sA[0][lds0 + 256]);
  async_copy16(gB, &sB[0][lds0]);
  async_copy16(gB + 32 * K, &sB[0][lds0 + 256]);

#pragma unroll 1
  for (int kt = 0; kt < NITER; ++kt) {
    int cur = kt & 1;
    __syncthreads();
    if (kt + 1 < NITER) {
      int nxt = cur ^ 1;
      int off = (kt + 1) * 64;
      async_copy16(gA + off, &sA[nxt][lds0]);
      async_copy16(gA + 32 * K + off, &sA[nxt][lds0 + 256]);
      async_copy16(gB + off, &sB[nxt][lds0]);
      async_copy16(gB + 32 * K + off, &sB[nxt][lds0 + 256]);
    }
#pragma unroll
    for (int ks = 0; ks < 2; ++ks) {
      int kg = ks * 4 + (lane >> 4);
      bf16x8 af[2], bfr[2];
      for (int i = 0; i < 2; ++i)
        af[i] = sA[cur][(wm + i * 16 + (lane & 15)) * 8 + kg];
      for (int j = 0; j < 2; ++j)
        bfr[j] = sB[cur][(wn + j * 16 + (lane & 15)) * 8 + kg];
      for (int i = 0; i < 2; ++i)
        for (int j = 0; j < 2; ++j)
          acc[i][j] = __builtin_amdgcn_mfma_f32_16x16x32_bf16(
              af[i], bfr[j], acc[i][j], 0, 0, 0);
    }
  }
  int row0 = bm * 64 + wm + ((lane >> 4) << 2);
  int col0 = bn * 64 + wn + (lane & 15);
  float* P = part + (size_t)s * (MDIM * DDIM);
  for (int i = 0; i < 2; ++i)
    for (int r = 0; r < 4; ++r) {
      float* Prow = P + (row0 + i * 16 + r) * DDIM + col0;
      for (int j = 0; j < 2; ++j)
        Prow[j * 16] = acc[i][j][r];
    }
}

// ---- combine + RK4 epilogue (vectorized float4 / ushort4) -----------------
// k = p0+p1+p2+p3 + b2
// mode 0: kacc = k;            arg = bf16(y + dt/2*k)
// mode 1: kacc += 2k;          arg = bf16(y + dt/2*k)
// mode 2: kacc += 2k;          arg = bf16(y + dt*k)
// mode 3: y += dt/6*(kacc+k);  arg = bf16(y_new)
__global__ __launch_bounds__(256) void combine_rk4_kernel(
    const float* __restrict__ part,          // [4][1024*512]
    const float* __restrict__ b2,
    float* __restrict__ y, float* __restrict__ kacc,
    unsigned short* __restrict__ arg, int mode, float dt)
{
  int t = blockIdx.x * 256 + threadIdx.x;    // 0..131071
  int base = t * 4;
  int col = base & (DDIM - 1);
  const float4* p0 = (const float4*)(part);
  const float4* p1 = (const float4*)(part + MDIM * DDIM);
  const float4* p2 = (const float4*)(part + 2 * MDIM * DDIM);
  const float4* p3 = (const float4*)(part + 3 * MDIM * DDIM);
  float4 a = p0[t], b = p1[t], c = p2[t], d = p3[t];
  float4 bb = *(const float4*)(b2 + col);
  float4 k;
  k.x = a.x + b.x + c.x + d.x + bb.x;
  k.y = a.y + b.y + c.y + d.y + bb.y;
  k.z = a.z + b.z + c.z + d.z + bb.z;
  k.w = a.w + b.w + c.w + d.w + bb.w;
  float4 yv = *(const float4*)(y + base);
  float4 argv;
  if (mode == 0) {
    *(float4*)(kacc + base) = k;
    float h = 0.5f * dt;
    argv.x = yv.x + h * k.x; argv.y = yv.y + h * k.y;
    argv.z = yv.z + h * k.z; argv.w = yv.w + h * k.w;
  } else if (mode == 1) {
    float4 ka = *(const float4*)(kacc + base);
    ka.x += 2.0f * k.x; ka.y += 2.0f * k.y; ka.z += 2.0f * k.z; ka.w += 2.0f * k.w;
    *(float4*)(kacc + base) = ka;
    float h = 0.5f * dt;
    argv.x = yv.x + h * k.x; argv.y = yv.y + h * k.y;
    argv.z = yv.z + h * k.z; argv.w = yv.w + h * k.w;
  } else if (mode == 2) {
    float4 ka = *(const float4*)(kacc + base);
    ka.x += 2.0f * k.x; ka.y += 2.0f * k.y; ka.z += 2.0f * k.z; ka.w += 2.0f * k.w;
    *(float4*)(kacc + base) = ka;
    argv.x = yv.x + dt * k.x; argv.y = yv.y + dt * k.y;
    argv.z = yv.z + dt * k.z; argv.w = yv.w + dt * k.w;
  } else {
    float4 ka = *(const float4*)(kacc + base);
    float s = dt * (1.0f / 6.0f);
    argv.x = yv.x + s * (ka.x + k.x); argv.y = yv.y + s * (ka.y + k.y);
    argv.z = yv.z + s * (ka.z + k.z); argv.w = yv.w + s * (ka.w + k.w);
    *(float4*)(y + base) = argv;
  }
  ushort4 av;
  av.x = f32_to_bf16(argv.x); av.y = f32_to_bf16(argv.y);
  av.z = f32_to_bf16(argv.z); av.w = f32_to_bf16(argv.w);
  *(ushort4*)(arg + base) = av;
}

extern "C" void kernel_launch(void* const* d_in, const int* in_sizes, int n_in,
                              void* d_out, int out_size, void* d_ws, size_t ws_size,
                              hipStream_t stream) {
  (void)in_sizes; (void)n_in; (void)out_size; (void)ws_size;
  const float* x  = (const float*)d_in[0];   // [1024,512]
  const float* W1 = (const float*)d_in[1];   // [512,2048]
  const float* b1 = (const float*)d_in[2];   // [2048]
  const float* W2 = (const float*)d_in[3];   // [2048,512]
  const float* b2 = (const float*)d_in[4];   // [512]
  float* y = (float*)d_out;                  // fp32 state lives in d_out

  char* ws = (char*)d_ws;
  unsigned short* W1T  = (unsigned short*)(ws);                    // 2MB  [2048,512] bf16
  unsigned short* W2T  = (unsigned short*)(ws + (2u << 20));       // 2MB  [512,2048] bf16
  unsigned short* Hbuf = (unsigned short*)(ws + (4u << 20));       // 4MB  [1024,2048] bf16
  unsigned short* arg  = (unsigned short*)(ws + (8u << 20));       // 1MB  [1024,512] bf16
  float*          kacc = (float*)(ws + (9u << 20));                // 2MB  [1024,512] f32
  float*          part = (float*)(ws + (11u << 20));               // 8MB  [4][1024,512] f32
  // total 19MB

  transpose_bf16_kernel<<<256, 256, 0, stream>>>(W1, W1T, DDIM, HDIM);
  transpose_bf16_kernel<<<256, 256, 0, stream>>>(W2, W2T, HDIM, DDIM);
  init_kernel<<<MDIM * DDIM / 256, 256, 0, stream>>>(x, y, arg);

  const float dt = 1.0f / 16.0f;
  for (int n = 0; n < 16; ++n) {
    float t0 = dt * (float)n;
    const float ts[4] = {t0, t0 + 0.5f * dt, t0 + 0.5f * dt, t0 + dt};
    for (int s = 0; s < 4; ++s) {
      gemm1_kernel<<<512, 256, 0, stream>>>(arg, W1T, b1, ts[s], Hbuf);
      gemm2_kernel<<<512, 256, 0, stream>>>(Hbuf, W2T, part);
      combine_rk4_kernel<<<512, 256, 0, stream>>>(part, b2, y, kacc, arg, s, dt);
    }
  }
}